// Round 6
// baseline (119.296 us; speedup 1.0000x reference)
//
#include <hip/hip_runtime.h>
#include <hip/hip_bf16.h>

// B=16, N=1024, M=8192.
//   d[b,n,m] = || binder[b,n,:] - target[m,:] ||
//   attract[b] = mean of 204 smallest (min_m d) over n;  repel[b] = sum relu(3-d)^2
//   out[b] = 10*attract + 5*repel
//
// R6 changes (R5 post-mortem: pair kernel stuck ~40us; VALUBusy 65% ~ 26us
// busy at ~1.8GHz + 35% stall on the per-iter dependent ds_read):
//  - NO LDS: prep kernel expands targets to duplicated packed layout
//    {-2tx,-2tx,-2ty,-2ty,-2tz,-2tz,|t|2,|t|2} so the pair loop reads
//    wave-uniform float2 -> s_load_dwordx8 into SGPR pairs (scalar pipe,
//    0 VALU issue, 4KB/chunk K$-resident).
//  - v2f packed math: 6 v_pk_fma_f32 replace 12 v_fma_f32; each pk_fma
//    reads one SGPR pair as the broadcast operand (legal: 1 sgpr src).
//  - defer |x|^2: min over f = |t|^2 - 2 t.x, add q per point after loop;
//    clash gate f < h with per-point h = 9 - q (4 VOPC + s_or, SALU).

typedef float v2f __attribute__((ext_vector_type(2)));

#define BB 16
#define NN 1024
#define MM 8192
#define MT 64           // targets per chunk
#define MC (MM / MT)    // 128 m-chunks
#define KSEL 204        // int(0.2 * 1024)

__global__ __launch_bounds__(256) void binder_prep_kernel(
    const float* __restrict__ target,   // [M, 3]
    float* __restrict__ prepped)        // [M, 8] duplicated packed
{
    const int i = blockIdx.x * 256 + threadIdx.x;   // 32 blocks x 256 = 8192
    const float tx = target[3 * i + 0];
    const float ty = target[3 * i + 1];
    const float tz = target[3 * i + 2];
    const float w  = fmaf(tx, tx, fmaf(ty, ty, tz * tz));
    float4* p = (float4*)(prepped + (size_t)i * 8);
    p[0] = make_float4(-2.0f * tx, -2.0f * tx, -2.0f * ty, -2.0f * ty);
    p[1] = make_float4(-2.0f * tz, -2.0f * tz, w, w);
}

__global__ __launch_bounds__(256, 8) void binder_pair_kernel(
    const float* __restrict__ binder,   // [B, N, 3]
    const float* __restrict__ prepped,  // [M, 8]
    float* __restrict__ min_part,       // [B, MC, N] min d^2 per chunk
    float* __restrict__ repel_part)     // [B, MC]
{
    __shared__ float wred[4];

    const int mc  = blockIdx.x;
    const int b   = blockIdx.y;
    const int tid = threadIdx.x;

    // 4 binder points per thread; 48B contiguous/lane, 16B-aligned.
    const float* bp = binder + ((size_t)b * NN + tid * 4) * 3;
    const float4 f0 = ((const float4*)bp)[0];
    const float4 f1 = ((const float4*)bp)[1];
    const float4 f2 = ((const float4*)bp)[2];
    const v2f x01 = {f0.x, f0.w};
    const v2f y01 = {f0.y, f1.x};
    const v2f z01 = {f0.z, f1.y};
    const v2f x23 = {f1.z, f2.y};
    const v2f y23 = {f1.w, f2.z};
    const v2f z23 = {f2.x, f2.w};
    const float q0 = fmaf(x01.x, x01.x, fmaf(y01.x, y01.x, z01.x * z01.x));
    const float q1 = fmaf(x01.y, x01.y, fmaf(y01.y, y01.y, z01.y * z01.y));
    const float q2 = fmaf(x23.x, x23.x, fmaf(y23.x, y23.x, z23.x * z23.x));
    const float q3 = fmaf(x23.y, x23.y, fmaf(y23.y, y23.y, z23.y * z23.y));
    const float h0 = 9.0f - q0, h1 = 9.0f - q1;
    const float h2 = 9.0f - q2, h3 = 9.0f - q3;

    // wave-uniform packed target stream for this chunk
    const v2f* sp = (const v2f*)(prepped + (size_t)mc * MT * 8);

    v2f m01 = {3.4e38f, 3.4e38f};
    v2f m23 = {3.4e38f, 3.4e38f};
    float repel = 0.0f;

#pragma unroll 4
    for (int m = 0; m < MT; ++m) {
        const v2f sx = sp[4 * m + 0];   // uniform -> s_load, SGPR pairs
        const v2f sy = sp[4 * m + 1];
        const v2f sz = sp[4 * m + 2];
        const v2f sw = sp[4 * m + 3];
        // f = |t|^2 - 2 t.x   (d^2 = f + q, deferred)
        const v2f f01 = x01 * sx + (y01 * sy + (z01 * sz + sw));
        const v2f f23 = x23 * sx + (y23 * sy + (z23 * sz + sw));
        m01.x = fminf(m01.x, f01.x);
        m01.y = fminf(m01.y, f01.y);
        m23.x = fminf(m23.x, f23.x);
        m23.y = fminf(m23.y, f23.y);
        const bool cl = (f01.x < h0) | (f01.y < h1) | (f23.x < h2) | (f23.y < h3);
        if (__any(cl)) {   // clash path (~47% of wave-iters)
            const float d0 = fmaxf(f01.x + q0, 0.0f);
            const float d1 = fmaxf(f01.y + q1, 0.0f);
            const float d2 = fmaxf(f23.x + q2, 0.0f);
            const float d3 = fmaxf(f23.y + q3, 0.0f);
            const float c0 = fmaxf(3.0f - __builtin_amdgcn_sqrtf(d0), 0.0f);
            const float c1 = fmaxf(3.0f - __builtin_amdgcn_sqrtf(d1), 0.0f);
            const float c2 = fmaxf(3.0f - __builtin_amdgcn_sqrtf(d2), 0.0f);
            const float c3 = fmaxf(3.0f - __builtin_amdgcn_sqrtf(d3), 0.0f);
            repel = fmaf(c0, c0, repel);
            repel = fmaf(c1, c1, repel);
            repel = fmaf(c2, c2, repel);
            repel = fmaf(c3, c3, repel);
        }
    }

    // re-attach q, clamp cancellation negatives; coalesced dwordx4 store
    const float4 mout = make_float4(fmaxf(m01.x + q0, 0.0f),
                                    fmaxf(m01.y + q1, 0.0f),
                                    fmaxf(m23.x + q2, 0.0f),
                                    fmaxf(m23.y + q3, 0.0f));
    ((float4*)min_part)[(size_t)(b * MC + mc) * (NN / 4) + tid] = mout;

    // repel block-reduce: wave shuffle then 4-slot LDS
#pragma unroll
    for (int off = 32; off > 0; off >>= 1) repel += __shfl_down(repel, off);
    if ((tid & 63) == 0) wred[tid >> 6] = repel;
    __syncthreads();
    if (tid == 0) repel_part[b * MC + mc] = wred[0] + wred[1] + wred[2] + wred[3];
}

// One block (256 thr) per batch. Fold MC rows -> 4 vals/thread, stage in LDS,
// per-wave redundant 31-step bit-bisection (no barriers in the loop), exact
// sum of KSEL smallest + ties. Then repel partial fold. Deterministic.
__global__ __launch_bounds__(256) void binder_reduce_kernel(
    const float* __restrict__ min_part,    // [B, MC, N]
    const float* __restrict__ repel_part,  // [B, MC]
    float* __restrict__ out)               // [B]
{
    __shared__ unsigned us[NN];
    __shared__ float wsum[4];
    __shared__ int   wcnt[4];
    __shared__ float rsum;

    const int b    = blockIdx.x;
    const int tid  = threadIdx.x;
    const int lane = tid & 63;
    const int wid  = tid >> 6;

    const float4* mp = (const float4*)min_part + (size_t)b * MC * (NN / 4) + tid;
    float4 a = mp[0];
    for (int c = 1; c < MC; ++c) {
        const float4 q = mp[(size_t)c * (NN / 4)];
        a.x = fminf(a.x, q.x); a.y = fminf(a.y, q.y);
        a.z = fminf(a.z, q.z); a.w = fminf(a.w, q.w);
    }
    unsigned u[4] = {__float_as_uint(a.x), __float_as_uint(a.y),
                     __float_as_uint(a.z), __float_as_uint(a.w)};
    us[tid * 4 + 0] = u[0];
    us[tid * 4 + 1] = u[1];
    us[tid * 4 + 2] = u[2];
    us[tid * 4 + 3] = u[3];
    __syncthreads();

    unsigned ub[16];
#pragma unroll
    for (int i = 0; i < 16; ++i) ub[i] = us[lane + 64 * i];

    // bisection: invariant count(x < lo) < KSEL; final lo = KSEL-th smallest.
    unsigned lo = 0u;
    for (int bit = 30; bit >= 0; --bit) {
        const unsigned mid = lo | (1u << bit);
        int c = 0;
#pragma unroll
        for (int i = 0; i < 16; ++i) c += (ub[i] < mid) ? 1 : 0;
#pragma unroll
        for (int off = 32; off > 0; off >>= 1) c += __shfl_down(c, off);
        c = __shfl(c, 0);
        if (c < KSEL) lo = mid;
    }

    float sum = 0.0f;
    int   cl  = 0;
#pragma unroll
    for (int i = 0; i < 4; ++i) {
        if (u[i] < lo) {
            sum += __builtin_amdgcn_sqrtf(__uint_as_float(u[i]));
            ++cl;
        }
    }
#pragma unroll
    for (int off = 32; off > 0; off >>= 1) {
        sum += __shfl_down(sum, off);
        cl  += __shfl_down(cl, off);
    }
    if (lane == 0) { wsum[wid] = sum; wcnt[wid] = cl; }

    if (wid == 0) {
        float r = repel_part[b * MC + lane] + repel_part[b * MC + 64 + lane];
#pragma unroll
        for (int off = 32; off > 0; off >>= 1) r += __shfl_down(r, off);
        if (lane == 0) rsum = r;
    }
    __syncthreads();

    if (tid == 0) {
        const float total = wsum[0] + wsum[1] + wsum[2] + wsum[3];
        const int   cnt   = wcnt[0] + wcnt[1] + wcnt[2] + wcnt[3];
        const float att   = total + (float)(KSEL - cnt)
                                    * __builtin_amdgcn_sqrtf(__uint_as_float(lo));
        out[b] = 10.0f * (att / (float)KSEL) + 5.0f * rsum;
    }
}

extern "C" void kernel_launch(void* const* d_in, const int* in_sizes, int n_in,
                              void* d_out, int out_size, void* d_ws, size_t ws_size,
                              hipStream_t stream) {
    const float* binder = (const float*)d_in[0];   // [16,1024,3] fp32
    const float* target = (const float*)d_in[1];   // [8192,3]   fp32
    float* out = (float*)d_out;                    // [16]       fp32

    float* prepped    = (float*)d_ws;                         // M*8 floats = 256 KiB
    float* min_part   = (float*)((char*)d_ws + (size_t)MM * 8 * sizeof(float));  // 8 MiB
    float* repel_part = (float*)((char*)d_ws + (size_t)MM * 8 * sizeof(float)
                                             + (size_t)BB * MC * NN * sizeof(float));

    binder_prep_kernel<<<MM / 256, 256, 0, stream>>>(target, prepped);
    dim3 g1(MC, BB);   // 128 x 16 = 2048 blocks
    binder_pair_kernel<<<g1, 256, 0, stream>>>(binder, prepped, min_part, repel_part);
    binder_reduce_kernel<<<BB, 256, 0, stream>>>(min_part, repel_part, out);
}